// Round 10
// baseline (290.636 us; speedup 1.0000x reference)
//
#include <hip/hip_runtime.h>
#include <math.h>
#include <stdint.h>

#define B_BATCH 4
#define T_SEQ   2048
#define C_EMB   1024
#define NH      16
#define HS      64

typedef _Float16 half_t;
typedef __attribute__((ext_vector_type(8))) _Float16 half8;   // 4 VGPRs, 16 B
typedef __attribute__((ext_vector_type(4))) _Float16 half4;   // 2 VGPRs, 8 B
typedef __attribute__((ext_vector_type(2))) __fp16 pk16x2;    // cvt_pkrtz result type
typedef __attribute__((ext_vector_type(4))) float f32x4;

// K=16 f16 MFMA; fallback = zero-padded K=32 (A/B agree on slot map -> same dot)
static __device__ __forceinline__ f32x4 mfma_k16(half4 a, half4 b, f32x4 c) {
#if __has_builtin(__builtin_amdgcn_mfma_f32_16x16x16f16)
    return __builtin_amdgcn_mfma_f32_16x16x16f16(a, b, c, 0, 0, 0);
#else
    half8 a8 = {a.x, a.y, a.z, a.w, (_Float16)0, (_Float16)0, (_Float16)0, (_Float16)0};
    half8 b8 = {b.x, b.y, b.z, b.w, (_Float16)0, (_Float16)0, (_Float16)0, (_Float16)0};
    return __builtin_amdgcn_mfma_f32_16x16x32_f16(a8, b8, c, 0, 0, 0);
#endif
}

// async global->LDS, 16B/lane; LDS dest = wave-uniform base + lane*16
static __device__ __forceinline__ void stage16(const void* g, void* lds_base) {
#if __has_builtin(__builtin_amdgcn_global_load_lds)
    __builtin_amdgcn_global_load_lds(
        (const __attribute__((address_space(1))) void*)g,
        (__attribute__((address_space(3))) void*)lds_base, 16, 0, 0);
#else
    const int lane = threadIdx.x & 63;
    ((uint4*)lds_base)[lane] = *(const uint4*)g;
#endif
}

// ---------------------------------------------------------------------------
// fp32 -> f16 elementwise (8 elems/thread)
// ---------------------------------------------------------------------------
__global__ __launch_bounds__(256) void f32_to_f16k(const float* __restrict__ src,
                                                   half_t* __restrict__ dst, int n8) {
    const int i = blockIdx.x * 256 + threadIdx.x;
    if (i >= n8) return;
    const float4 a = *(const float4*)(src + (size_t)i * 8);
    const float4 b = *(const float4*)(src + (size_t)i * 8 + 4);
    const pk16x2 h0 = __builtin_amdgcn_cvt_pkrtz(a.x, a.y);
    const pk16x2 h1 = __builtin_amdgcn_cvt_pkrtz(a.z, a.w);
    const pk16x2 h2 = __builtin_amdgcn_cvt_pkrtz(b.x, b.y);
    const pk16x2 h3 = __builtin_amdgcn_cvt_pkrtz(b.z, b.w);
    half8 o = {(_Float16)h0.x, (_Float16)h0.y, (_Float16)h1.x, (_Float16)h1.y,
               (_Float16)h2.x, (_Float16)h2.y, (_Float16)h3.x, (_Float16)h3.y};
    *(half8*)(dst + (size_t)i * 8) = o;
}

// ---------------------------------------------------------------------------
// W[K][N] fp32 -> WT[N][K] f16, 64x64 LDS tile
// ---------------------------------------------------------------------------
__global__ __launch_bounds__(256) void transpose_f32_f16(const float* __restrict__ W,
                                                         half_t* __restrict__ WT,
                                                         int K, int N) {
    __shared__ float t[64][65];
    const int k0 = blockIdx.y * 64, n0 = blockIdx.x * 64;
    const int tid = threadIdx.x;
    const int r = tid >> 4, c4 = (tid & 15) * 4;
#pragma unroll
    for (int p = 0; p < 4; ++p) {
        const float4 g = *(const float4*)(W + (size_t)(k0 + p * 16 + r) * N + n0 + c4);
        t[p * 16 + r][c4 + 0] = g.x;
        t[p * 16 + r][c4 + 1] = g.y;
        t[p * 16 + r][c4 + 2] = g.z;
        t[p * 16 + r][c4 + 3] = g.w;
    }
    __syncthreads();
#pragma unroll
    for (int p = 0; p < 4; ++p) {
        const int n = p * 16 + r;
        half4 s = {(_Float16)t[c4 + 0][n], (_Float16)t[c4 + 1][n],
                   (_Float16)t[c4 + 2][n], (_Float16)t[c4 + 3][n]};
        *(half4*)(WT + (size_t)(n0 + n) * K + k0 + c4) = s;
    }
}

// ---------------------------------------------------------------------------
// f16 MFMA GEMM (m97 structure): C[M,N] = A[M,K] @ Bt[N,K]^T
// SPLIT_V: columns >= 2048 are the V part of qkv -> written transposed to
//   vT[b][h][d][t] as packed half4 along t (branch is wave-uniform per nt).
// ---------------------------------------------------------------------------
template <int OUT_MODE>   // 0 = f32, 1 = f16, 2 = f16 + split-V
__global__ __launch_bounds__(256) void gemm_bt(const half_t* __restrict__ A,
                                               const half_t* __restrict__ Bt,
                                               void* __restrict__ Cout,
                                               half_t* __restrict__ vT,
                                               int M, int N, int K) {
    __shared__ half_t As[128 * 32];
    __shared__ half_t Bs[128 * 32];

    const int tid  = threadIdx.x;
    const int lane = tid & 63;
    const int wid  = tid >> 6;
    const int l16  = lane & 15;
    const int quad = lane >> 4;

    const int m0 = blockIdx.y * 128;
    const int n0 = blockIdx.x * 128;
    const int wm = (wid >> 1) * 64;
    const int wn = (wid & 1) * 64;

    const half_t* gA0 = A  + (size_t)(m0 + wid * 16      + (lane >> 2)) * K + (lane & 3) * 8;
    const half_t* gA1 = A  + (size_t)(m0 + wid * 16 + 64 + (lane >> 2)) * K + (lane & 3) * 8;
    const half_t* gB0 = Bt + (size_t)(n0 + wid * 16      + (lane >> 2)) * K + (lane & 3) * 8;
    const half_t* gB1 = Bt + (size_t)(n0 + wid * 16 + 64 + (lane >> 2)) * K + (lane & 3) * 8;

    half_t* lA0 = As + (size_t)wid * 512;
    half_t* lA1 = As + (size_t)(wid + 4) * 512;
    half_t* lB0 = Bs + (size_t)wid * 512;
    half_t* lB1 = Bs + (size_t)(wid + 4) * 512;

    f32x4 acc[4][4];
#pragma unroll
    for (int i = 0; i < 4; ++i)
#pragma unroll
        for (int j = 0; j < 4; ++j) acc[i][j] = (f32x4){0.f, 0.f, 0.f, 0.f};

    for (int k0 = 0; k0 < K; k0 += 32) {
        __syncthreads();
        stage16(gA0 + k0, lA0);
        stage16(gA1 + k0, lA1);
        stage16(gB0 + k0, lB0);
        stage16(gB1 + k0, lB1);
        __syncthreads();

        half8 fa[4], fb[4];
#pragma unroll
        for (int mt = 0; mt < 4; ++mt)
            fa[mt] = *(const half8*)(As + (wm + mt * 16 + l16) * 32 + quad * 8);
#pragma unroll
        for (int nt = 0; nt < 4; ++nt)
            fb[nt] = *(const half8*)(Bs + (wn + nt * 16 + l16) * 32 + quad * 8);
#pragma unroll
        for (int mt = 0; mt < 4; ++mt)
#pragma unroll
            for (int nt = 0; nt < 4; ++nt)
                acc[mt][nt] = __builtin_amdgcn_mfma_f32_16x16x32_f16(
                    fa[mt], fb[nt], acc[mt][nt], 0, 0, 0);
    }

#pragma unroll
    for (int mt = 0; mt < 4; ++mt)
#pragma unroll
        for (int nt = 0; nt < 4; ++nt) {
            const int col     = n0 + wn + nt * 16 + l16;
            const int rowbase = m0 + wm + mt * 16 + quad * 4;
            if constexpr (OUT_MODE == 2) {
                if (col >= 2 * C_EMB) {   // V part -> vT[b][h][d][t], t-contig
                    const int hh = (col - 2 * C_EMB) >> 6;
                    const int dd = (col - 2 * C_EMB) & 63;
                    const int bb = rowbase >> 11;
                    const int tt = rowbase & 2047;
                    half4 pk = {(_Float16)acc[mt][nt][0], (_Float16)acc[mt][nt][1],
                                (_Float16)acc[mt][nt][2], (_Float16)acc[mt][nt][3]};
                    *(half4*)(vT + (((size_t)bb * NH + hh) * HS + dd) * T_SEQ + tt) = pk;
                    continue;
                }
            }
#pragma unroll
            for (int r = 0; r < 4; ++r) {
                const size_t row = rowbase + r;
                if constexpr (OUT_MODE == 0)
                    ((float*)Cout)[row * N + col] = acc[mt][nt][r];
                else
                    ((half_t*)Cout)[row * N + col] = (half_t)acc[mt][nt][r];
            }
        }
}

// ---------------------------------------------------------------------------
// MFMA flash attention v4: Bc=128, pre-transposed V, balanced pairs.
// Grid: 1024 = 64 (b,h) groups x 16 pair-slots; block does qh=31-s then qh=s.
// Tiles per job = (qh>>1)+1  =>  pair total = 17 always (exact balance).
// XCD: g = L & 63, 64 % 8 == 0 -> all blocks of a group on one XCD.
// V comes pre-transposed from gemm1 (vT[b][h][d][t]) -> staging is plain
// coalesced half8 copies (no repack VALU, no scatter conflicts).
// Diagonal: global mask k0+kcol > q0+qrel on the last tile only.
// LDS: Kl[128][72] (K tile, Q staged in first 64 rows pre-loop),
//      Vt[64][136] (V^T tile, also O staging at epilogue), Lstat[64]. 36.1 KB.
// ---------------------------------------------------------------------------
#define KL_STRIDE 72
#define VT_STRIDE 136
#define SCALE_EXP2 0.18033688f   // 0.125 * log2(e)

__global__ __launch_bounds__(256, 4) void attn_mfma(const half_t* __restrict__ qkv,
                                                    const half_t* __restrict__ vT,
                                                    half_t* __restrict__ y) {
    __shared__ half_t Kl[128 * KL_STRIDE];   // 18432 B
    __shared__ half_t Vt[64 * VT_STRIDE];    // 17408 B
    __shared__ float Lstat[64];

    const int tid  = threadIdx.x;
    const int wid  = tid >> 6;
    const int lane = tid & 63;
    const int l16  = lane & 15;
    const int quad = lane >> 4;

    const int L = blockIdx.x;
    const int g = L & 63;                 // (b,h) group -> fixed XCD (g % 8)
    const int s = L >> 6;                 // pair slot 0..15
    const int h = g & 15;
    const int b = g >> 4;

    const size_t rs = 3 * C_EMB;
    const half_t* qb  = qkv + (size_t)b * T_SEQ * rs + h * HS;
    const half_t* kb  = qb + C_EMB;
    const half_t* vTb = vT + ((size_t)b * NH + h) * HS * T_SEQ;   // [d][t]

    // staging decodes
    const int qrow_s = tid >> 2, qcol_s = (tid & 3) * 16;   // Q: 64 rows x 16 halfs
    const int krow_s = tid >> 1, kcol_s = (tid & 1) * 32;   // K: 128 rows x 32 halfs
    const int vrow_s = tid >> 2, vcol_s = (tid & 3) * 32;   // V^T: 64 rows x 32 halfs

    const int qrel = wid * 16 + l16;      // q-row within tile (for diag mask)

#pragma unroll 1
    for (int j = 0; j < 2; ++j) {
        const int qh = (j == 0) ? (31 - s) : s;
        const int q0 = qh * 64;
        const int ntile = (qh >> 1) + 1;

        // ---- stage Q into Kl rows 0..63 ----
        __syncthreads();   // prior job's LDS reads done
        {
            const half_t* src = qb + (size_t)(q0 + qrow_s) * rs + qcol_s;
            half_t* dst = Kl + qrow_s * KL_STRIDE + qcol_s;
            *(half8*)(dst)     = *(const half8*)(src);
            *(half8*)(dst + 8) = *(const half8*)(src + 8);
        }
        __syncthreads();

        half8 aQ[2];
#pragma unroll
        for (int s2 = 0; s2 < 2; ++s2)
            aQ[s2] = *(const half8*)(Kl + (wid * 16 + l16) * KL_STRIDE + s2 * 32 + quad * 8);

        f32x4 O[4];
#pragma unroll
        for (int dt = 0; dt < 4; ++dt) O[dt] = (f32x4){0.f, 0.f, 0.f, 0.f};
        float lw = 0.f;

        for (int kt = 0; kt < ntile; ++kt) {
            const int k0 = kt * 128;
            const bool last = (kt == ntile - 1);
            __syncthreads();   // prior tile frag reads done (first: aQ reads done)

            // ---- stage K: Kl[kcol][d], 128 rows ----
            {
                const half_t* src = kb + (size_t)(k0 + krow_s) * rs + kcol_s;
                half_t* dst = Kl + krow_s * KL_STRIDE + kcol_s;
                *(half8*)(dst)      = *(const half8*)(src);
                *(half8*)(dst + 8)  = *(const half8*)(src + 8);
                *(half8*)(dst + 16) = *(const half8*)(src + 16);
                *(half8*)(dst + 24) = *(const half8*)(src + 24);
            }
            // ---- stage V^T: plain coalesced copies from vT ----
            {
                const half_t* src = vTb + (size_t)vrow_s * T_SEQ + k0 + vcol_s;
                half_t* dst = Vt + vrow_s * VT_STRIDE + vcol_s;
                *(half8*)(dst)      = *(const half8*)(src);
                *(half8*)(dst + 8)  = *(const half8*)(src + 8);
                *(half8*)(dst + 16) = *(const half8*)(src + 16);
                *(half8*)(dst + 24) = *(const half8*)(src + 24);
            }
            __syncthreads();

            // ---- fused: S^T MFMA -> exp2 -> P frag -> O += P@V ----
#pragma unroll
            for (int mt = 0; mt < 8; ++mt) {
                const half8 aK0 = *(const half8*)(Kl + (mt * 16 + l16) * KL_STRIDE + quad * 8);
                const half8 aK1 = *(const half8*)(Kl + (mt * 16 + l16) * KL_STRIDE + 32 + quad * 8);
                f32x4 sa = (f32x4){0.f, 0.f, 0.f, 0.f};
                sa = __builtin_amdgcn_mfma_f32_16x16x32_f16(aK0, aQ[0], sa, 0, 0, 0);
                sa = __builtin_amdgcn_mfma_f32_16x16x32_f16(aK1, aQ[1], sa, 0, 0, 0);

                float p[4];
#pragma unroll
                for (int r = 0; r < 4; ++r)
                    p[r] = __builtin_amdgcn_exp2f(sa[r] * SCALE_EXP2);
                if (last) {
                    const int kbase = k0 + mt * 16 + quad * 4;
#pragma unroll
                    for (int r = 0; r < 4; ++r)
                        if (kbase + r > q0 + qrel) p[r] = 0.f;
                }
                lw += (p[0] + p[1]) + (p[2] + p[3]);

                const half4 pa = {(_Float16)p[0], (_Float16)p[1],
                                  (_Float16)p[2], (_Float16)p[3]};
#pragma unroll
                for (int dt = 0; dt < 4; ++dt) {
                    const half4 bV = *(const half4*)(Vt + (dt * 16 + l16) * VT_STRIDE +
                                                     mt * 16 + quad * 4);
                    O[dt] = mfma_k16(pa, bV, O[dt]);
                }
            }
        }

        // ---- epilogue: l-reduce, normalize, coalesced store via LDS ----
        lw += __shfl_xor(lw, 16);
        lw += __shfl_xor(lw, 32);
        if (quad == 0) Lstat[wid * 16 + l16] = lw;   // wave-private exchange
        __syncthreads();   // all waves done reading Vt -> safe to overwrite
#pragma unroll
        for (int r = 0; r < 4; ++r) {
            const int rowl = wid * 16 + quad * 4 + r;
            const float inv = 1.f / Lstat[rowl];
#pragma unroll
            for (int dt = 0; dt < 4; ++dt)
                Vt[rowl * VT_STRIDE + dt * 16 + l16] = (half_t)(O[dt][r] * inv);
        }
        __syncthreads();
        {
            half_t* dst = y + ((size_t)b * T_SEQ + q0 + qrow_s) * C_EMB + h * HS + qcol_s;
            const half_t* src = Vt + qrow_s * VT_STRIDE + qcol_s;
            *(half8*)(dst)     = *(const half8*)(src);
            *(half8*)(dst + 8) = *(const half8*)(src + 8);
        }
    }
}

// ---------------------------------------------------------------------------
extern "C" void kernel_launch(void* const* d_in, const int* in_sizes, int n_in,
                              void* d_out, int out_size, void* d_ws, size_t ws_size,
                              hipStream_t stream) {
    const float* x      = (const float*)d_in[0];   // [8192,1024]
    const float* w_attn = (const float*)d_in[1];   // [1024,3072]
    const float* w_proj = (const float*)d_in[2];   // [1024,1024]
    float* out = (float*)d_out;

    half_t* xh   = (half_t*)d_ws;                        // 16 MB
    half_t* waT  = xh   + (size_t)8192 * 1024;           //  6 MB [3072][1024]
    half_t* wpT  = waT  + (size_t)3072 * 1024;           //  2 MB [1024][1024]
    half_t* qkvh = wpT  + (size_t)1024 * 1024;           // 48 MB [8192][3072] (v third unused)
    half_t* yh   = qkvh + (size_t)8192 * 3072;           // 16 MB [8192][1024]
    half_t* vTt  = yh   + (size_t)8192 * 1024;           // 16 MB [4][16][64][2048]

    f32_to_f16k<<<4096, 256, 0, stream>>>(x, xh, 8192 * 1024 / 8);
    transpose_f32_f16<<<dim3(48, 16), 256, 0, stream>>>(w_attn, waT, 1024, 3072);
    transpose_f32_f16<<<dim3(16, 16), 256, 0, stream>>>(w_proj, wpT, 1024, 1024);

    // qkv = x @ w_attn   (f16 out; V part written transposed to vTt)
    gemm_bt<2><<<dim3(24, 64), 256, 0, stream>>>(xh, waT, qkvh, vTt, 8192, 3072, 1024);

    // attention (1024 balanced pair-blocks, XCD-swizzled, Bc=128)
    attn_mfma<<<dim3(1024), 256, 0, stream>>>(qkvh, vTt, yh);

    // out = y @ w_proj   (fp32 out)
    gemm_bt<0><<<dim3(8, 64), 256, 0, stream>>>(yh, wpT, out, nullptr, 8192, 1024, 1024);
}

// Round 11
// 276.705 us; speedup vs baseline: 1.0503x; 1.0503x over previous
//
#include <hip/hip_runtime.h>
#include <math.h>
#include <stdint.h>

#define B_BATCH 4
#define T_SEQ   2048
#define C_EMB   1024
#define NH      16
#define HS      64

typedef _Float16 half_t;
typedef __attribute__((ext_vector_type(8))) _Float16 half8;   // 4 VGPRs, 16 B
typedef __attribute__((ext_vector_type(4))) _Float16 half4;   // 2 VGPRs, 8 B
typedef __attribute__((ext_vector_type(2))) __fp16 pk16x2;    // cvt_pkrtz result type
typedef __attribute__((ext_vector_type(4))) float f32x4;

// K=16 f16 MFMA; fallback = zero-padded K=32 (A/B agree on slot map -> same dot)
static __device__ __forceinline__ f32x4 mfma_k16(half4 a, half4 b, f32x4 c) {
#if __has_builtin(__builtin_amdgcn_mfma_f32_16x16x16f16)
    return __builtin_amdgcn_mfma_f32_16x16x16f16(a, b, c, 0, 0, 0);
#else
    half8 a8 = {a.x, a.y, a.z, a.w, (_Float16)0, (_Float16)0, (_Float16)0, (_Float16)0};
    half8 b8 = {b.x, b.y, b.z, b.w, (_Float16)0, (_Float16)0, (_Float16)0, (_Float16)0};
    return __builtin_amdgcn_mfma_f32_16x16x32_f16(a8, b8, c, 0, 0, 0);
#endif
}

// async global->LDS, 16B/lane; LDS dest = wave-uniform base + lane*16
static __device__ __forceinline__ void stage16(const void* g, void* lds_base) {
#if __has_builtin(__builtin_amdgcn_global_load_lds)
    __builtin_amdgcn_global_load_lds(
        (const __attribute__((address_space(1))) void*)g,
        (__attribute__((address_space(3))) void*)lds_base, 16, 0, 0);
#else
    const int lane = threadIdx.x & 63;
    ((uint4*)lds_base)[lane] = *(const uint4*)g;
#endif
}

// ---------------------------------------------------------------------------
// fp32 -> f16 elementwise (8 elems/thread)
// ---------------------------------------------------------------------------
__global__ __launch_bounds__(256) void f32_to_f16k(const float* __restrict__ src,
                                                   half_t* __restrict__ dst, int n8) {
    const int i = blockIdx.x * 256 + threadIdx.x;
    if (i >= n8) return;
    const float4 a = *(const float4*)(src + (size_t)i * 8);
    const float4 b = *(const float4*)(src + (size_t)i * 8 + 4);
    const pk16x2 h0 = __builtin_amdgcn_cvt_pkrtz(a.x, a.y);
    const pk16x2 h1 = __builtin_amdgcn_cvt_pkrtz(a.z, a.w);
    const pk16x2 h2 = __builtin_amdgcn_cvt_pkrtz(b.x, b.y);
    const pk16x2 h3 = __builtin_amdgcn_cvt_pkrtz(b.z, b.w);
    half8 o = {(_Float16)h0.x, (_Float16)h0.y, (_Float16)h1.x, (_Float16)h1.y,
               (_Float16)h2.x, (_Float16)h2.y, (_Float16)h3.x, (_Float16)h3.y};
    *(half8*)(dst + (size_t)i * 8) = o;
}

// ---------------------------------------------------------------------------
// W[K][N] fp32 -> WT[N][K] f16, 64x64 LDS tile
// ---------------------------------------------------------------------------
__global__ __launch_bounds__(256) void transpose_f32_f16(const float* __restrict__ W,
                                                         half_t* __restrict__ WT,
                                                         int K, int N) {
    __shared__ float t[64][65];
    const int k0 = blockIdx.y * 64, n0 = blockIdx.x * 64;
    const int tid = threadIdx.x;
    const int r = tid >> 4, c4 = (tid & 15) * 4;
#pragma unroll
    for (int p = 0; p < 4; ++p) {
        const float4 g = *(const float4*)(W + (size_t)(k0 + p * 16 + r) * N + n0 + c4);
        t[p * 16 + r][c4 + 0] = g.x;
        t[p * 16 + r][c4 + 1] = g.y;
        t[p * 16 + r][c4 + 2] = g.z;
        t[p * 16 + r][c4 + 3] = g.w;
    }
    __syncthreads();
#pragma unroll
    for (int p = 0; p < 4; ++p) {
        const int n = p * 16 + r;
        half4 s = {(_Float16)t[c4 + 0][n], (_Float16)t[c4 + 1][n],
                   (_Float16)t[c4 + 2][n], (_Float16)t[c4 + 3][n]};
        *(half4*)(WT + (size_t)(n0 + n) * K + k0 + c4) = s;
    }
}

// ---------------------------------------------------------------------------
// f16 MFMA GEMM (m97 structure): C[M,N] = A[M,K] @ Bt[N,K]^T
// OUT_F16: epilogue coalesced via per-wave LDS transpose bounce (f32 col-major
// write, row-major readback, 32-B contiguous f16 global stores; 4 lanes/row
// cover 128 B). Removes the 2-B-scatter write amplification (attn round-9
// precedent: 169 MB -> 16 MB).
// ---------------------------------------------------------------------------
template <bool OUT_F16>
__global__ __launch_bounds__(256) void gemm_bt(const half_t* __restrict__ A,
                                               const half_t* __restrict__ Bt,
                                               void* __restrict__ Cout,
                                               int M, int N, int K) {
    __shared__ __align__(16) half_t SM[2 * 128 * 32];   // As | Bs, 16 KB
    half_t* As = SM;
    half_t* Bs = SM + 128 * 32;

    const int tid  = threadIdx.x;
    const int lane = tid & 63;
    const int wid  = tid >> 6;
    const int l16  = lane & 15;
    const int quad = lane >> 4;

    const int m0 = blockIdx.y * 128;
    const int n0 = blockIdx.x * 128;
    const int wm = (wid >> 1) * 64;
    const int wn = (wid & 1) * 64;

    const half_t* gA0 = A  + (size_t)(m0 + wid * 16      + (lane >> 2)) * K + (lane & 3) * 8;
    const half_t* gA1 = A  + (size_t)(m0 + wid * 16 + 64 + (lane >> 2)) * K + (lane & 3) * 8;
    const half_t* gB0 = Bt + (size_t)(n0 + wid * 16      + (lane >> 2)) * K + (lane & 3) * 8;
    const half_t* gB1 = Bt + (size_t)(n0 + wid * 16 + 64 + (lane >> 2)) * K + (lane & 3) * 8;

    half_t* lA0 = As + (size_t)wid * 512;
    half_t* lA1 = As + (size_t)(wid + 4) * 512;
    half_t* lB0 = Bs + (size_t)wid * 512;
    half_t* lB1 = Bs + (size_t)(wid + 4) * 512;

    f32x4 acc[4][4];
#pragma unroll
    for (int i = 0; i < 4; ++i)
#pragma unroll
        for (int j = 0; j < 4; ++j) acc[i][j] = (f32x4){0.f, 0.f, 0.f, 0.f};

    for (int k0 = 0; k0 < K; k0 += 32) {
        __syncthreads();
        stage16(gA0 + k0, lA0);
        stage16(gA1 + k0, lA1);
        stage16(gB0 + k0, lB0);
        stage16(gB1 + k0, lB1);
        __syncthreads();

        half8 fa[4], fb[4];
#pragma unroll
        for (int mt = 0; mt < 4; ++mt)
            fa[mt] = *(const half8*)(As + (wm + mt * 16 + l16) * 32 + quad * 8);
#pragma unroll
        for (int nt = 0; nt < 4; ++nt)
            fb[nt] = *(const half8*)(Bs + (wn + nt * 16 + l16) * 32 + quad * 8);
#pragma unroll
        for (int mt = 0; mt < 4; ++mt)
#pragma unroll
            for (int nt = 0; nt < 4; ++nt)
                acc[mt][nt] = __builtin_amdgcn_mfma_f32_16x16x32_f16(
                    fa[mt], fb[nt], acc[mt][nt], 0, 0, 0);
    }

    if constexpr (OUT_F16) {
        __syncthreads();   // all waves done with As/Bs frag reads
        float* cw = (float*)SM + wid * 1024;   // per-wave 16 rows x 64 cols, col-major
        const int rrow = lane >> 2;            // 0..15
        const int cseg = (lane & 3) * 16;      // 0,16,32,48
#pragma unroll
        for (int mt = 0; mt < 4; ++mt) {
#pragma unroll
            for (int nt = 0; nt < 4; ++nt)
                *(f32x4*)&cw[(nt * 16 + l16) * 16 + quad * 4] = acc[mt][nt];
            // wave-internal LDS dep: DS ops are processed in order per wave
            half_t tmp[16];
#pragma unroll
            for (int jj = 0; jj < 16; ++jj)
                tmp[jj] = (half_t)cw[(cseg + jj) * 16 + rrow];
            half_t* dst = (half_t*)Cout + (size_t)(m0 + wm + mt * 16 + rrow) * N
                          + n0 + wn + cseg;
            *(half8*)(dst)     = *(const half8*)(tmp);
            *(half8*)(dst + 8) = *(const half8*)(tmp + 8);
        }
    } else {
#pragma unroll
        for (int mt = 0; mt < 4; ++mt)
#pragma unroll
            for (int nt = 0; nt < 4; ++nt)
#pragma unroll
                for (int r = 0; r < 4; ++r) {
                    const size_t row = m0 + wm + mt * 16 + quad * 4 + r;
                    const size_t col = n0 + wn + nt * 16 + l16;
                    ((float*)Cout)[row * N + col] = acc[mt][nt][r];
                }
    }
}

// ---------------------------------------------------------------------------
// MFMA flash attention v3 (round-9 proven version): balanced pairs, Bc=64,
// coalesced epilogue. Grid: 1024 = 64 (b,h) groups x 16 pair-slots; block
// does qh=31-s then qh=s => exactly 33 k-tiles per block (perfect balance).
// XCD: g = L & 63, 64 % 8 == 0 -> all blocks of a group on one XCD.
// LDS: Kl[64][72] (K tile + Q staging), Vt[64][72] (V^T + O staging),
// Lstat[64]. 18.7 KB -> 4 blocks/CU.
// ---------------------------------------------------------------------------
#define KL_STRIDE 72
#define VT_STRIDE 72
#define SCALE_EXP2 0.18033688f   // 0.125 * log2(e)

__global__ __launch_bounds__(256, 4) void attn_mfma(const half_t* __restrict__ qkv,
                                                    half_t* __restrict__ y) {
    __shared__ half_t Kl[64 * KL_STRIDE];
    __shared__ half_t Vt[64 * VT_STRIDE];
    __shared__ float Lstat[64];

    const int tid  = threadIdx.x;
    const int wid  = tid >> 6;
    const int lane = tid & 63;
    const int l16  = lane & 15;
    const int quad = lane >> 4;

    const int L = blockIdx.x;
    const int g = L & 63;                 // (b,h) group -> fixed XCD (g % 8)
    const int s = L >> 6;                 // pair slot 0..15
    const int h = g & 15;
    const int b = g >> 4;

    const size_t rs = 3 * C_EMB;
    const half_t* qb = qkv + (size_t)b * T_SEQ * rs + h * HS;
    const half_t* kb = qb + C_EMB;
    const half_t* vb = qb + 2 * C_EMB;

    // staging decode: 4 threads/row, 16 halfs (2 x half8) each
    const int srow = tid >> 2;            // 0..63
    const int scol = (tid & 3) * 16;      // 0,16,32,48
    // V-transpose decode
    const int rp   = tid & 31;            // row pair: rows 2rp, 2rp+1
    const int dblk = tid >> 5;            // 0..7 -> d = dblk*8 .. +8

    const int qrel = wid * 16 + l16;      // q-row within tile (for diag mask)

#pragma unroll 1
    for (int j = 0; j < 2; ++j) {
        const int qh = (j == 0) ? (31 - s) : s;
        const int q0 = qh * 64;

        // ---- stage Q into Kl (full rows: two half8 per thread) ----
        __syncthreads();   // prior job's LDS reads done
        {
            const half_t* src = qb + (size_t)(q0 + srow) * rs + scol;
            half_t* dst = Kl + srow * KL_STRIDE + scol;
            *(half8*)(dst)     = *(const half8*)(src);
            *(half8*)(dst + 8) = *(const half8*)(src + 8);
        }
        __syncthreads();

        half8 aQ[2];
#pragma unroll
        for (int s2 = 0; s2 < 2; ++s2)
            aQ[s2] = *(const half8*)(Kl + (wid * 16 + l16) * KL_STRIDE + s2 * 32 + quad * 8);

        f32x4 O[4];
#pragma unroll
        for (int dt = 0; dt < 4; ++dt) O[dt] = (f32x4){0.f, 0.f, 0.f, 0.f};
        float lw = 0.f;

        for (int kt = 0; kt <= qh; ++kt) {
            const int k0 = kt * 64;
            const bool diag = (kt == qh);
            __syncthreads();   // prior tile frag reads done (first: aQ reads done)

            // ---- stage K: Kl[kcol][d] (full rows) ----
            {
                const half_t* src = kb + (size_t)(k0 + srow) * rs + scol;
                half_t* dst = Kl + srow * KL_STRIDE + scol;
                *(half8*)(dst)     = *(const half8*)(src);
                *(half8*)(dst + 8) = *(const half8*)(src + 8);
            }
            // ---- stage V^T: Vt[d][kcol], paired-row b32 packing ----
            {
                const uint4 va = *(const uint4*)(vb + (size_t)(k0 + 2 * rp) * rs + dblk * 8);
                const uint4 vc = *(const uint4*)(vb + (size_t)(k0 + 2 * rp + 1) * rs + dblk * 8);
                const uint32_t a[4] = {va.x, va.y, va.z, va.w};
                const uint32_t c[4] = {vc.x, vc.y, vc.z, vc.w};
                unsigned short* vts = (unsigned short*)Vt;
#pragma unroll
                for (int u = 0; u < 4; ++u) {
                    const int d0 = dblk * 8 + 2 * u;
                    const uint32_t w0 = (a[u] & 0xffffu) | (c[u] << 16);
                    const uint32_t w1 = (a[u] >> 16) | (c[u] & 0xffff0000u);
                    *(uint32_t*)(vts + (d0 + 0) * VT_STRIDE + 2 * rp) = w0;
                    *(uint32_t*)(vts + (d0 + 1) * VT_STRIDE + 2 * rp) = w1;
                }
            }
            __syncthreads();

            // ---- fused: S^T MFMA -> exp2 -> P frag -> O += P@V ----
#pragma unroll
            for (int mt = 0; mt < 4; ++mt) {
                const half8 aK0 = *(const half8*)(Kl + (mt * 16 + l16) * KL_STRIDE + quad * 8);
                const half8 aK1 = *(const half8*)(Kl + (mt * 16 + l16) * KL_STRIDE + 32 + quad * 8);
                f32x4 sa = (f32x4){0.f, 0.f, 0.f, 0.f};
                sa = __builtin_amdgcn_mfma_f32_16x16x32_f16(aK0, aQ[0], sa, 0, 0, 0);
                sa = __builtin_amdgcn_mfma_f32_16x16x32_f16(aK1, aQ[1], sa, 0, 0, 0);

                const int kbase = mt * 16 + quad * 4;
                float p[4];
#pragma unroll
                for (int r = 0; r < 4; ++r)
                    p[r] = __builtin_amdgcn_exp2f(sa[r] * SCALE_EXP2);
                if (diag) {
#pragma unroll
                    for (int r = 0; r < 4; ++r)
                        if (kbase + r > qrel) p[r] = 0.f;
                }
                lw += (p[0] + p[1]) + (p[2] + p[3]);

                const half4 pa = {(_Float16)p[0], (_Float16)p[1],
                                  (_Float16)p[2], (_Float16)p[3]};
#pragma unroll
                for (int dt = 0; dt < 4; ++dt) {
                    const half4 bV = *(const half4*)(Vt + (dt * 16 + l16) * VT_STRIDE +
                                                     mt * 16 + quad * 4);
                    O[dt] = mfma_k16(pa, bV, O[dt]);
                }
            }
        }

        // ---- epilogue: l-reduce, normalize, coalesced store via LDS ----
        lw += __shfl_xor(lw, 16);
        lw += __shfl_xor(lw, 32);
        if (quad == 0) Lstat[wid * 16 + l16] = lw;   // wave-private exchange
        __syncthreads();   // all waves done reading Vt -> safe to overwrite
#pragma unroll
        for (int r = 0; r < 4; ++r) {
            const int rowl = wid * 16 + quad * 4 + r;
            const float inv = 1.f / Lstat[rowl];
#pragma unroll
            for (int dt = 0; dt < 4; ++dt)
                Vt[rowl * VT_STRIDE + dt * 16 + l16] = (half_t)(O[dt][r] * inv);
        }
        __syncthreads();
        {
            half_t* dst = y + ((size_t)b * T_SEQ + q0 + srow) * C_EMB + h * HS + scol;
            const half_t* src = Vt + srow * VT_STRIDE + scol;
            *(half8*)(dst)     = *(const half8*)(src);
            *(half8*)(dst + 8) = *(const half8*)(src + 8);
        }
    }
}

// ---------------------------------------------------------------------------
extern "C" void kernel_launch(void* const* d_in, const int* in_sizes, int n_in,
                              void* d_out, int out_size, void* d_ws, size_t ws_size,
                              hipStream_t stream) {
    const float* x      = (const float*)d_in[0];   // [8192,1024]
    const float* w_attn = (const float*)d_in[1];   // [1024,3072]
    const float* w_proj = (const float*)d_in[2];   // [1024,1024]
    float* out = (float*)d_out;

    half_t* xh   = (half_t*)d_ws;                        // 16 MB
    half_t* waT  = xh   + (size_t)8192 * 1024;           //  6 MB [3072][1024]
    half_t* wpT  = waT  + (size_t)3072 * 1024;           //  2 MB [1024][1024]
    half_t* qkvh = wpT  + (size_t)1024 * 1024;           // 48 MB [8192][3072]
    half_t* yh   = qkvh + (size_t)8192 * 3072;           // 16 MB [8192][1024]

    f32_to_f16k<<<4096, 256, 0, stream>>>(x, xh, 8192 * 1024 / 8);
    transpose_f32_f16<<<dim3(48, 16), 256, 0, stream>>>(w_attn, waT, 1024, 3072);
    transpose_f32_f16<<<dim3(16, 16), 256, 0, stream>>>(w_proj, wpT, 1024, 1024);

    // qkv = x @ w_attn   (f16 out, coalesced epilogue)
    gemm_bt<true><<<dim3(24, 64), 256, 0, stream>>>(xh, waT, qkvh, 8192, 3072, 1024);

    // attention (1024 balanced pair-blocks, XCD-swizzled)
    attn_mfma<<<dim3(1024), 256, 0, stream>>>(qkvh, yh);

    // out = y @ w_proj   (fp32 out)
    gemm_bt<false><<<dim3(8, 64), 256, 0, stream>>>(yh, wpT, out, 8192, 1024, 1024);
}

// Round 12
// 276.482 us; speedup vs baseline: 1.0512x; 1.0008x over previous
//
#include <hip/hip_runtime.h>
#include <math.h>
#include <stdint.h>

#define B_BATCH 4
#define T_SEQ   2048
#define C_EMB   1024
#define NH      16
#define HS      64

typedef _Float16 half_t;
typedef __attribute__((ext_vector_type(8))) _Float16 half8;   // 4 VGPRs, 16 B
typedef __attribute__((ext_vector_type(4))) _Float16 half4;   // 2 VGPRs, 8 B
typedef __attribute__((ext_vector_type(2))) __fp16 pk16x2;    // cvt_pkrtz result type
typedef __attribute__((ext_vector_type(4))) float f32x4;

// K=16 f16 MFMA; fallback = zero-padded K=32 (A/B agree on slot map -> same dot)
static __device__ __forceinline__ f32x4 mfma_k16(half4 a, half4 b, f32x4 c) {
#if __has_builtin(__builtin_amdgcn_mfma_f32_16x16x16f16)
    return __builtin_amdgcn_mfma_f32_16x16x16f16(a, b, c, 0, 0, 0);
#else
    half8 a8 = {a.x, a.y, a.z, a.w, (_Float16)0, (_Float16)0, (_Float16)0, (_Float16)0};
    half8 b8 = {b.x, b.y, b.z, b.w, (_Float16)0, (_Float16)0, (_Float16)0, (_Float16)0};
    return __builtin_amdgcn_mfma_f32_16x16x32_f16(a8, b8, c, 0, 0, 0);
#endif
}

// async global->LDS, 16B/lane; LDS dest = wave-uniform base + lane*16
static __device__ __forceinline__ void stage16(const void* g, void* lds_base) {
#if __has_builtin(__builtin_amdgcn_global_load_lds)
    __builtin_amdgcn_global_load_lds(
        (const __attribute__((address_space(1))) void*)g,
        (__attribute__((address_space(3))) void*)lds_base, 16, 0, 0);
#else
    const int lane = threadIdx.x & 63;
    ((uint4*)lds_base)[lane] = *(const uint4*)g;
#endif
}

// ---------------------------------------------------------------------------
// Merged prep: fp32->f16 convert of x  +  both weight transposes.
// Grid partition: [0,4096) convert, [4096,4864) w_attn T, [4864,5120) w_proj T.
// ---------------------------------------------------------------------------
__global__ __launch_bounds__(256) void prep_kernel(const float* __restrict__ x,
                                                   half_t* __restrict__ xh,
                                                   const float* __restrict__ wa,
                                                   half_t* __restrict__ waT,
                                                   const float* __restrict__ wp,
                                                   half_t* __restrict__ wpT) {
    const int blk = blockIdx.x;
    const int tid = threadIdx.x;

    if (blk < 4096) {   // x convert: 8 elems/thread
        const int i = blk * 256 + tid;
        const float4 a = *(const float4*)(x + (size_t)i * 8);
        const float4 b = *(const float4*)(x + (size_t)i * 8 + 4);
        const pk16x2 h0 = __builtin_amdgcn_cvt_pkrtz(a.x, a.y);
        const pk16x2 h1 = __builtin_amdgcn_cvt_pkrtz(a.z, a.w);
        const pk16x2 h2 = __builtin_amdgcn_cvt_pkrtz(b.x, b.y);
        const pk16x2 h3 = __builtin_amdgcn_cvt_pkrtz(b.z, b.w);
        half8 o = {(_Float16)h0.x, (_Float16)h0.y, (_Float16)h1.x, (_Float16)h1.y,
                   (_Float16)h2.x, (_Float16)h2.y, (_Float16)h3.x, (_Float16)h3.y};
        *(half8*)(xh + (size_t)i * 8) = o;
        return;
    }

    // weight transpose: W[K][N] f32 -> WT[N][K] f16, 64x64 tile
    const float* W;
    half_t* WT;
    int K, N, bb;
    if (blk < 4096 + 768) {
        bb = blk - 4096; W = wa; WT = waT; K = 1024; N = 3072;
        // 48 n-tiles x 16 k-tiles
    } else {
        bb = blk - 4864; W = wp; WT = wpT; K = 1024; N = 1024;
    }
    const int ntiles = N / 64;
    const int n0 = (bb % ntiles) * 64;
    const int k0 = (bb / ntiles) * 64;

    __shared__ float t[64][65];
    const int r = tid >> 4, c4 = (tid & 15) * 4;
#pragma unroll
    for (int p = 0; p < 4; ++p) {
        const float4 g = *(const float4*)(W + (size_t)(k0 + p * 16 + r) * N + n0 + c4);
        t[p * 16 + r][c4 + 0] = g.x;
        t[p * 16 + r][c4 + 1] = g.y;
        t[p * 16 + r][c4 + 2] = g.z;
        t[p * 16 + r][c4 + 3] = g.w;
    }
    __syncthreads();
#pragma unroll
    for (int p = 0; p < 4; ++p) {
        const int n = p * 16 + r;
        half4 s = {(_Float16)t[c4 + 0][n], (_Float16)t[c4 + 1][n],
                   (_Float16)t[c4 + 2][n], (_Float16)t[c4 + 3][n]};
        *(half4*)(WT + (size_t)(n0 + n) * K + k0 + c4) = s;
    }
}

// ---------------------------------------------------------------------------
// f16 MFMA GEMM (m97 structure): C[M,N] = A[M,K] @ Bt[N,K]^T, 128x128 tile.
// f16 out, coalesced epilogue via per-wave LDS transpose bounce.
// ---------------------------------------------------------------------------
__global__ __launch_bounds__(256) void gemm_bt_f16(const half_t* __restrict__ A,
                                                   const half_t* __restrict__ Bt,
                                                   half_t* __restrict__ Cout,
                                                   int M, int N, int K) {
    __shared__ __align__(16) half_t SM[2 * 128 * 32];   // As | Bs, 16 KB
    half_t* As = SM;
    half_t* Bs = SM + 128 * 32;

    const int tid  = threadIdx.x;
    const int lane = tid & 63;
    const int wid  = tid >> 6;
    const int l16  = lane & 15;
    const int quad = lane >> 4;

    const int m0 = blockIdx.y * 128;
    const int n0 = blockIdx.x * 128;
    const int wm = (wid >> 1) * 64;
    const int wn = (wid & 1) * 64;

    const half_t* gA0 = A  + (size_t)(m0 + wid * 16      + (lane >> 2)) * K + (lane & 3) * 8;
    const half_t* gA1 = A  + (size_t)(m0 + wid * 16 + 64 + (lane >> 2)) * K + (lane & 3) * 8;
    const half_t* gB0 = Bt + (size_t)(n0 + wid * 16      + (lane >> 2)) * K + (lane & 3) * 8;
    const half_t* gB1 = Bt + (size_t)(n0 + wid * 16 + 64 + (lane >> 2)) * K + (lane & 3) * 8;

    half_t* lA0 = As + (size_t)wid * 512;
    half_t* lA1 = As + (size_t)(wid + 4) * 512;
    half_t* lB0 = Bs + (size_t)wid * 512;
    half_t* lB1 = Bs + (size_t)(wid + 4) * 512;

    f32x4 acc[4][4];
#pragma unroll
    for (int i = 0; i < 4; ++i)
#pragma unroll
        for (int j = 0; j < 4; ++j) acc[i][j] = (f32x4){0.f, 0.f, 0.f, 0.f};

    for (int k0 = 0; k0 < K; k0 += 32) {
        __syncthreads();
        stage16(gA0 + k0, lA0);
        stage16(gA1 + k0, lA1);
        stage16(gB0 + k0, lB0);
        stage16(gB1 + k0, lB1);
        __syncthreads();

        half8 fa[4], fb[4];
#pragma unroll
        for (int mt = 0; mt < 4; ++mt)
            fa[mt] = *(const half8*)(As + (wm + mt * 16 + l16) * 32 + quad * 8);
#pragma unroll
        for (int nt = 0; nt < 4; ++nt)
            fb[nt] = *(const half8*)(Bs + (wn + nt * 16 + l16) * 32 + quad * 8);
#pragma unroll
        for (int mt = 0; mt < 4; ++mt)
#pragma unroll
            for (int nt = 0; nt < 4; ++nt)
                acc[mt][nt] = __builtin_amdgcn_mfma_f32_16x16x32_f16(
                    fa[mt], fb[nt], acc[mt][nt], 0, 0, 0);
    }

    __syncthreads();   // all waves done with As/Bs frag reads
    float* cw = (float*)SM + wid * 1024;   // per-wave 16 rows x 64 cols, col-major
    const int rrow = lane >> 2;            // 0..15
    const int cseg = (lane & 3) * 16;      // 0,16,32,48
#pragma unroll
    for (int mt = 0; mt < 4; ++mt) {
#pragma unroll
        for (int nt = 0; nt < 4; ++nt)
            *(f32x4*)&cw[(nt * 16 + l16) * 16 + quad * 4] = acc[mt][nt];
        // wave-internal LDS dep: DS ops are processed in order per wave
        half_t tmp[16];
#pragma unroll
        for (int jj = 0; jj < 16; ++jj)
            tmp[jj] = (half_t)cw[(cseg + jj) * 16 + rrow];
        half_t* dst = Cout + (size_t)(m0 + wm + mt * 16 + rrow) * N + n0 + wn + cseg;
        *(half8*)(dst)     = *(const half8*)(tmp);
        *(half8*)(dst + 8) = *(const half8*)(tmp + 8);
    }
}

// ---------------------------------------------------------------------------
// f16 MFMA GEMM, 64x128 tile (for N=1024 shapes: 2x the blocks of 128x128).
// Wave = 32x64 (2x4 of 16x16x32). f32 out, scalar coalesced stores.
// ---------------------------------------------------------------------------
__global__ __launch_bounds__(256) void gemm_bt_a64(const half_t* __restrict__ A,
                                                   const half_t* __restrict__ Bt,
                                                   float* __restrict__ Cout,
                                                   int M, int N, int K) {
    __shared__ half_t As[64 * 32];    //  4 KB
    __shared__ half_t Bs[128 * 32];   //  8 KB

    const int tid  = threadIdx.x;
    const int lane = tid & 63;
    const int wid  = tid >> 6;
    const int l16  = lane & 15;
    const int quad = lane >> 4;

    const int m0 = blockIdx.y * 64;
    const int n0 = blockIdx.x * 128;
    const int wm = (wid & 1) * 32;
    const int wn = (wid >> 1) * 64;

    const half_t* gA  = A  + (size_t)(m0 + wid * 16      + (lane >> 2)) * K + (lane & 3) * 8;
    const half_t* gB0 = Bt + (size_t)(n0 + wid * 16      + (lane >> 2)) * K + (lane & 3) * 8;
    const half_t* gB1 = Bt + (size_t)(n0 + wid * 16 + 64 + (lane >> 2)) * K + (lane & 3) * 8;

    half_t* lA  = As + (size_t)wid * 512;
    half_t* lB0 = Bs + (size_t)wid * 512;
    half_t* lB1 = Bs + (size_t)(wid + 4) * 512;

    f32x4 acc[2][4];
#pragma unroll
    for (int i = 0; i < 2; ++i)
#pragma unroll
        for (int j = 0; j < 4; ++j) acc[i][j] = (f32x4){0.f, 0.f, 0.f, 0.f};

    for (int k0 = 0; k0 < K; k0 += 32) {
        __syncthreads();
        stage16(gA + k0, lA);
        stage16(gB0 + k0, lB0);
        stage16(gB1 + k0, lB1);
        __syncthreads();

        half8 fa[2], fb[4];
#pragma unroll
        for (int mt = 0; mt < 2; ++mt)
            fa[mt] = *(const half8*)(As + (wm + mt * 16 + l16) * 32 + quad * 8);
#pragma unroll
        for (int nt = 0; nt < 4; ++nt)
            fb[nt] = *(const half8*)(Bs + (wn + nt * 16 + l16) * 32 + quad * 8);
#pragma unroll
        for (int mt = 0; mt < 2; ++mt)
#pragma unroll
            for (int nt = 0; nt < 4; ++nt)
                acc[mt][nt] = __builtin_amdgcn_mfma_f32_16x16x32_f16(
                    fa[mt], fb[nt], acc[mt][nt], 0, 0, 0);
    }

#pragma unroll
    for (int mt = 0; mt < 2; ++mt)
#pragma unroll
        for (int nt = 0; nt < 4; ++nt)
#pragma unroll
            for (int r = 0; r < 4; ++r) {
                const size_t row = m0 + wm + mt * 16 + quad * 4 + r;
                const size_t col = n0 + wn + nt * 16 + l16;
                Cout[row * N + col] = acc[mt][nt][r];
            }
}

// ---------------------------------------------------------------------------
// MFMA flash attention v3 (round-9 proven version): balanced pairs, Bc=64,
// coalesced epilogue. Grid: 1024 = 64 (b,h) groups x 16 pair-slots; block
// does qh=31-s then qh=s => exactly 33 k-tiles per block (perfect balance).
// XCD: g = L & 63, 64 % 8 == 0 -> all blocks of a group on one XCD.
// LDS: Kl[64][72] (K tile + Q staging), Vt[64][72] (V^T + O staging),
// Lstat[64]. 18.7 KB -> 4 blocks/CU.
// ---------------------------------------------------------------------------
#define KL_STRIDE 72
#define VT_STRIDE 72
#define SCALE_EXP2 0.18033688f   // 0.125 * log2(e)

__global__ __launch_bounds__(256, 4) void attn_mfma(const half_t* __restrict__ qkv,
                                                    half_t* __restrict__ y) {
    __shared__ half_t Kl[64 * KL_STRIDE];
    __shared__ half_t Vt[64 * VT_STRIDE];
    __shared__ float Lstat[64];

    const int tid  = threadIdx.x;
    const int wid  = tid >> 6;
    const int lane = tid & 63;
    const int l16  = lane & 15;
    const int quad = lane >> 4;

    const int L = blockIdx.x;
    const int g = L & 63;                 // (b,h) group -> fixed XCD (g % 8)
    const int s = L >> 6;                 // pair slot 0..15
    const int h = g & 15;
    const int b = g >> 4;

    const size_t rs = 3 * C_EMB;
    const half_t* qb = qkv + (size_t)b * T_SEQ * rs + h * HS;
    const half_t* kb = qb + C_EMB;
    const half_t* vb = qb + 2 * C_EMB;

    // staging decode: 4 threads/row, 16 halfs (2 x half8) each
    const int srow = tid >> 2;            // 0..63
    const int scol = (tid & 3) * 16;      // 0,16,32,48
    // V-transpose decode
    const int rp   = tid & 31;            // row pair: rows 2rp, 2rp+1
    const int dblk = tid >> 5;            // 0..7 -> d = dblk*8 .. +8

    const int qrel = wid * 16 + l16;      // q-row within tile (for diag mask)

#pragma unroll 1
    for (int j = 0; j < 2; ++j) {
        const int qh = (j == 0) ? (31 - s) : s;
        const int q0 = qh * 64;

        // ---- stage Q into Kl (full rows: two half8 per thread) ----
        __syncthreads();   // prior job's LDS reads done
        {
            const half_t* src = qb + (size_t)(q0 + srow) * rs + scol;
            half_t* dst = Kl + srow * KL_STRIDE + scol;
            *(half8*)(dst)     = *(const half8*)(src);
            *(half8*)(dst + 8) = *(const half8*)(src + 8);
        }
        __syncthreads();

        half8 aQ[2];
#pragma unroll
        for (int s2 = 0; s2 < 2; ++s2)
            aQ[s2] = *(const half8*)(Kl + (wid * 16 + l16) * KL_STRIDE + s2 * 32 + quad * 8);

        f32x4 O[4];
#pragma unroll
        for (int dt = 0; dt < 4; ++dt) O[dt] = (f32x4){0.f, 0.f, 0.f, 0.f};
        float lw = 0.f;

        for (int kt = 0; kt <= qh; ++kt) {
            const int k0 = kt * 64;
            const bool diag = (kt == qh);
            __syncthreads();   // prior tile frag reads done (first: aQ reads done)

            // ---- stage K: Kl[kcol][d] (full rows) ----
            {
                const half_t* src = kb + (size_t)(k0 + srow) * rs + scol;
                half_t* dst = Kl + srow * KL_STRIDE + scol;
                *(half8*)(dst)     = *(const half8*)(src);
                *(half8*)(dst + 8) = *(const half8*)(src + 8);
            }
            // ---- stage V^T: Vt[d][kcol], paired-row b32 packing ----
            {
                const uint4 va = *(const uint4*)(vb + (size_t)(k0 + 2 * rp) * rs + dblk * 8);
                const uint4 vc = *(const uint4*)(vb + (size_t)(k0 + 2 * rp + 1) * rs + dblk * 8);
                const uint32_t a[4] = {va.x, va.y, va.z, va.w};
                const uint32_t c[4] = {vc.x, vc.y, vc.z, vc.w};
                unsigned short* vts = (unsigned short*)Vt;
#pragma unroll
                for (int u = 0; u < 4; ++u) {
                    const int d0 = dblk * 8 + 2 * u;
                    const uint32_t w0 = (a[u] & 0xffffu) | (c[u] << 16);
                    const uint32_t w1 = (a[u] >> 16) | (c[u] & 0xffff0000u);
                    *(uint32_t*)(vts + (d0 + 0) * VT_STRIDE + 2 * rp) = w0;
                    *(uint32_t*)(vts + (d0 + 1) * VT_STRIDE + 2 * rp) = w1;
                }
            }
            __syncthreads();

            // ---- fused: S^T MFMA -> exp2 -> P frag -> O += P@V ----
#pragma unroll
            for (int mt = 0; mt < 4; ++mt) {
                const half8 aK0 = *(const half8*)(Kl + (mt * 16 + l16) * KL_STRIDE + quad * 8);
                const half8 aK1 = *(const half8*)(Kl + (mt * 16 + l16) * KL_STRIDE + 32 + quad * 8);
                f32x4 sa = (f32x4){0.f, 0.f, 0.f, 0.f};
                sa = __builtin_amdgcn_mfma_f32_16x16x32_f16(aK0, aQ[0], sa, 0, 0, 0);
                sa = __builtin_amdgcn_mfma_f32_16x16x32_f16(aK1, aQ[1], sa, 0, 0, 0);

                const int kbase = mt * 16 + quad * 4;
                float p[4];
#pragma unroll
                for (int r = 0; r < 4; ++r)
                    p[r] = __builtin_amdgcn_exp2f(sa[r] * SCALE_EXP2);
                if (diag) {
#pragma unroll
                    for (int r = 0; r < 4; ++r)
                        if (kbase + r > qrel) p[r] = 0.f;
                }
                lw += (p[0] + p[1]) + (p[2] + p[3]);

                const half4 pa = {(_Float16)p[0], (_Float16)p[1],
                                  (_Float16)p[2], (_Float16)p[3]};
#pragma unroll
                for (int dt = 0; dt < 4; ++dt) {
                    const half4 bV = *(const half4*)(Vt + (dt * 16 + l16) * VT_STRIDE +
                                                     mt * 16 + quad * 4);
                    O[dt] = mfma_k16(pa, bV, O[dt]);
                }
            }
        }

        // ---- epilogue: l-reduce, normalize, coalesced store via LDS ----
        lw += __shfl_xor(lw, 16);
        lw += __shfl_xor(lw, 32);
        if (quad == 0) Lstat[wid * 16 + l16] = lw;   // wave-private exchange
        __syncthreads();   // all waves done reading Vt -> safe to overwrite
#pragma unroll
        for (int r = 0; r < 4; ++r) {
            const int rowl = wid * 16 + quad * 4 + r;
            const float inv = 1.f / Lstat[rowl];
#pragma unroll
            for (int dt = 0; dt < 4; ++dt)
                Vt[rowl * VT_STRIDE + dt * 16 + l16] = (half_t)(O[dt][r] * inv);
        }
        __syncthreads();
        {
            half_t* dst = y + ((size_t)b * T_SEQ + q0 + srow) * C_EMB + h * HS + scol;
            const half_t* src = Vt + srow * VT_STRIDE + scol;
            *(half8*)(dst)     = *(const half8*)(src);
            *(half8*)(dst + 8) = *(const half8*)(src + 8);
        }
    }
}

// ---------------------------------------------------------------------------
extern "C" void kernel_launch(void* const* d_in, const int* in_sizes, int n_in,
                              void* d_out, int out_size, void* d_ws, size_t ws_size,
                              hipStream_t stream) {
    const float* x      = (const float*)d_in[0];   // [8192,1024]
    const float* w_attn = (const float*)d_in[1];   // [1024,3072]
    const float* w_proj = (const float*)d_in[2];   // [1024,1024]
    float* out = (float*)d_out;

    half_t* xh   = (half_t*)d_ws;                        // 16 MB
    half_t* waT  = xh   + (size_t)8192 * 1024;           //  6 MB [3072][1024]
    half_t* wpT  = waT  + (size_t)3072 * 1024;           //  2 MB [1024][1024]
    half_t* qkvh = wpT  + (size_t)1024 * 1024;           // 48 MB [8192][3072]
    half_t* yh   = qkvh + (size_t)8192 * 3072;           // 16 MB [8192][1024]

    // merged prep: x convert + both weight transposes
    prep_kernel<<<5120, 256, 0, stream>>>(x, xh, w_attn, waT, w_proj, wpT);

    // qkv = x @ w_attn   (f16 out, coalesced epilogue)
    gemm_bt_f16<<<dim3(24, 64), 256, 0, stream>>>(xh, waT, qkvh, 8192, 3072, 1024);

    // attention (1024 balanced pair-blocks, XCD-swizzled)
    attn_mfma<<<dim3(1024), 256, 0, stream>>>(qkvh, yh);

    // out = y @ w_proj   (fp32 out, 64x128 tiles -> 1024 blocks)
    gemm_bt_a64<<<dim3(8, 128), 256, 0, stream>>>(yh, wpT, out, 8192, 1024, 1024);
}